// Round 5
// baseline (191.688 us; speedup 1.0000x reference)
//
#include <hip/hip_runtime.h>

// DMoE (PLE/CGC) fused kernel for MI355X (gfx950).
// B=32768, D_IN=256, H=128, N_TASK=2, N_EXP=4, N_SHARE=4.
//
// R5: attack L2 same-line broadcast contention (unified theory of R1-R4:
// dur ~= total weight traffic / ~5 TB/s effective).
//  - t-merged, BM=128, grid 256, 512 thr: weight traffic 256 x 811 KB = 208 MB
//    (was 604 MB in R4).
//  - weight image REPLICATED NC<=4 times in d_ws; block uses copy
//    (blk>>3)%NC so same-XCD blocks cycle through copies -> 4x more distinct
//    L2 lines servicing the broadcast.
//  - staging unit = half-expert (128h x 136k bf16 = 34816 B), reg-pipelined
//    global->VGPR->ds_write, double buffer selected by kh (compile-time).
//    ~600-cycle compute phase per unit covers L2 latency at distance 1.
//  - A-frags resident (64 VGPR); row stride 272 B spreads LDS banks evenly.

typedef __attribute__((ext_vector_type(8))) short short8;   // 8 x bf16
typedef __attribute__((ext_vector_type(4))) float float4v;  // MFMA C/D

#define ROW_US     136        // 128 data + 8 pad (bf16)
#define ROW_B      272
#define UNIT_US    17408      // 128 rows x 136
#define UNIT_B     34816
#define WAVE_B     4352       // UNIT_B / 8 waves
#define WGT_OFF_US 417792     // 24 * 17408
#define COPY_US    421888     // + 16*256 gate ushorts
#define COPY_B     843776

__device__ __forceinline__ unsigned short f2bf(float f) {
  unsigned u = __builtin_bit_cast(unsigned, f);
  u += 0x7FFFu + ((u >> 16) & 1u);   // round-to-nearest-even
  return (unsigned short)(u >> 16);
}

// ---------------------------------------------------------------------------
// Prep: WT[c][e][kh] units (128h x 136k bf16) + WgT[16][256] per copy.
__global__ __launch_bounds__(256)
void prep_kernel(const float* __restrict__ Ws,
                 const float* __restrict__ Wt,
                 const float* __restrict__ Wg,
                 unsigned short* __restrict__ WT, int NC) {
  int bid = blockIdx.x;
  int tid = threadIdx.x;
  if (bid < 96) {
    __shared__ float tile[64][65];
    int e  = bid >> 3;
    int kt = (bid >> 1) & 3;   // 64-wide k tile; kh = kt>>1, half-local = kt&1
    int ht = bid & 1;          // h half
    const float* src = (e < 4) ? Ws + ((size_t)e << 15)
                               : Wt + ((size_t)(e - 4) << 15);
    int m = tid & 15, n = tid >> 4;
    #pragma unroll
    for (int i = 0; i < 4; ++i) {   // coalesced read of src[k][h]
      int kl = i * 16 + n;
      float4 v = *(const float4*)&src[(size_t)(kt * 64 + kl) * 128 + ht * 64 + m * 4];
      tile[kl][m * 4 + 0] = v.x;
      tile[kl][m * 4 + 1] = v.y;
      tile[kl][m * 4 + 2] = v.z;
      tile[kl][m * 4 + 3] = v.w;
    }
    __syncthreads();
    #pragma unroll
    for (int i = 0; i < 4; ++i) {
      int hl = i * 16 + n;
      ushort4 o;
      o.x = f2bf(tile[m * 4 + 0][hl]);
      o.y = f2bf(tile[m * 4 + 1][hl]);
      o.z = f2bf(tile[m * 4 + 2][hl]);
      o.w = f2bf(tile[m * 4 + 3][hl]);
      size_t rowbase = (size_t)(e * 2 + (kt >> 1)) * UNIT_US
                     + (size_t)(ht * 64 + hl) * ROW_US + (kt & 1) * 64;
      for (int c = 0; c < NC; ++c) {
        *(ushort4*)&WT[(size_t)c * COPY_US + rowbase + m * 4] = o;
        if ((kt & 1) == 1 && m < 2) {           // zero row pad [128,136)
          ushort4 z = {0, 0, 0, 0};
          *(ushort4*)&WT[(size_t)c * COPY_US + rowbase + 64 + m * 4] = z;
        }
      }
    }
  } else {
    // gate weights WgT[n][256], n = t*8+g
    #pragma unroll
    for (int it = 0; it < 16; ++it) {
      int j = it * 256 + tid;
      int n = j >> 8, k = j & 255;
      int t = n >> 3, g = n & 7;
      unsigned short v = f2bf(Wg[(size_t)(t * 256 + k) * 8 + g]);
      for (int c = 0; c < NC; ++c)
        WT[(size_t)c * COPY_US + WGT_OFF_US + j] = v;
    }
  }
}

// ---------------------------------------------------------------------------
__global__ __launch_bounds__(512, 2)
void dmoe_main(const float* __restrict__ x,
               const unsigned short* __restrict__ WT,
               const float* __restrict__ b_share,
               const float* __restrict__ b_task,
               const float* __restrict__ b_gate,
               float* __restrict__ out, int NC) {
  __shared__ unsigned short Bs0[UNIT_US];   // 34816 B
  __shared__ unsigned short Bs1[UNIT_US];   // 34816 B
  __shared__ float gatesL[16 * 132];        // [gate-col][row(128)+pad]
  __shared__ float biasLds[12 * 128];       // 6144 B

  const int tid  = threadIdx.x;
  const int lane = tid & 63;
  const int w    = tid >> 6;    // wave 0..7
  const int col  = lane & 15;
  const int quad = lane >> 4;
  const int mg   = w >> 1;      // rows [mg*32, mg*32+32)
  const int ng   = w & 1;       // h    [ng*64, ng*64+64)
  const int blk  = blockIdx.x;

  const char* WTc = (const char*)WT + (size_t)((blk >> 3) % NC) * COPY_B;

  // ---- issue unit-0 loads first (longest latency) ----
  uint4 p0, p1, p2, p3; unsigned p4;
  {
    const char* g = WTc + w * WAVE_B;
    p0 = *(const uint4*)(g + lane * 16);
    p1 = *(const uint4*)(g + 1024 + lane * 16);
    p2 = *(const uint4*)(g + 2048 + lane * 16);
    p3 = *(const uint4*)(g + 3072 + lane * 16);
    p4 = *(const unsigned*)(g + 4096 + lane * 4);
  }

  // ---- A-fragments: 2 m-tiles x 8 k-steps resident ----
  short8 A[2][8];
  {
    const float* xb = x + ((size_t)blk * 128 + mg * 32 + col) * 256 + quad * 8;
    #pragma unroll
    for (int mt = 0; mt < 2; ++mt) {
      const float* xr = xb + (size_t)mt * 16 * 256;
      #pragma unroll
      for (int k = 0; k < 8; ++k) {
        float4 u = *(const float4*)(xr + k * 32);
        float4 v = *(const float4*)(xr + k * 32 + 4);
        short8 fr;
        fr[0] = (short)f2bf(u.x); fr[1] = (short)f2bf(u.y);
        fr[2] = (short)f2bf(u.z); fr[3] = (short)f2bf(u.w);
        fr[4] = (short)f2bf(v.x); fr[5] = (short)f2bf(v.y);
        fr[6] = (short)f2bf(v.z); fr[7] = (short)f2bf(v.w);
        A[mt][k] = fr;
      }
    }
  }

  // ---- biases -> LDS ----
  for (int i = tid; i < 1536; i += 512)
    biasLds[i] = (i < 512) ? b_share[i] : b_task[i - 512];

  // ---- gates (t-merged: 16 logit cols; col>>3 = task) ----
  {
    const unsigned short* WgT = (const unsigned short*)(WTc + WGT_OFF_US * 2);
    const unsigned short* bp = WgT + (size_t)col * 256 + quad * 8;
    short8 Bg[8];
    #pragma unroll
    for (int k = 0; k < 8; ++k) Bg[k] = *(const short8*)(bp + k * 32);
    float bg = b_gate[col];
    #pragma unroll
    for (int mt = 0; mt < 2; ++mt) {
      float4v ag = {0.f, 0.f, 0.f, 0.f};
      #pragma unroll
      for (int k = 0; k < 8; ++k)
        ag = __builtin_amdgcn_mfma_f32_16x16x32_bf16(A[mt][k], Bg[k], ag, 0, 0, 0);
      #pragma unroll
      for (int r = 0; r < 4; ++r) {
        float vlog = ag[r] + bg;
        float m = vlog;                      // softmax over 8 cols in t-half
        m = fmaxf(m, __shfl_xor(m, 1));
        m = fmaxf(m, __shfl_xor(m, 2));
        m = fmaxf(m, __shfl_xor(m, 4));
        float p = __expf(vlog - m);
        float s = p;
        s += __shfl_xor(s, 1);
        s += __shfl_xor(s, 2);
        s += __shfl_xor(s, 4);
        if (ng == 0)
          gatesL[col * 132 + mg * 32 + mt * 16 + quad * 4 + r] = p / s;
      }
    }
  }

  // ---- deposit unit 0 into Bs0 ----
  {
    char* l = (char*)Bs0 + w * WAVE_B;
    *(uint4*)(l + lane * 16)        = p0;
    *(uint4*)(l + 1024 + lane * 16) = p1;
    *(uint4*)(l + 2048 + lane * 16) = p2;
    *(uint4*)(l + 3072 + lane * 16) = p3;
    *(unsigned*)(l + 4096 + lane * 4) = p4;
  }
  __syncthreads();

  // ---- accumulators ----
  float tw[2][2][4][4];   // [task][mt][nt][r]
  #pragma unroll
  for (int t = 0; t < 2; ++t)
    #pragma unroll
    for (int mt = 0; mt < 2; ++mt)
      #pragma unroll
      for (int nt = 0; nt < 4; ++nt)
        #pragma unroll
        for (int r = 0; r < 4; ++r)
          tw[t][mt][nt][r] = 0.f;

  const int hb = ng * 64;
  float4v acc[2][4];

  // ---- expert loop: 12 experts x 2 k-halves; buffer = kh (compile-time) ----
  #pragma unroll 1
  for (int e = 0; e < 12; ++e) {
    #pragma unroll
    for (int kh = 0; kh < 2; ++kh) {
      const int u = e * 2 + kh;
      // prefetch next unit
      uint4 q0, q1, q2, q3; unsigned q4;
      const bool doStage = (u < 23);
      if (doStage) {
        const char* g = WTc + (size_t)(u + 1) * UNIT_B + w * WAVE_B;
        q0 = *(const uint4*)(g + lane * 16);
        q1 = *(const uint4*)(g + 1024 + lane * 16);
        q2 = *(const uint4*)(g + 2048 + lane * 16);
        q3 = *(const uint4*)(g + 3072 + lane * 16);
        q4 = *(const unsigned*)(g + 4096 + lane * 4);
      }
      if (kh == 0) {
        #pragma unroll
        for (int mt = 0; mt < 2; ++mt)
          #pragma unroll
          for (int nt = 0; nt < 4; ++nt)
            acc[mt][nt] = (float4v){0.f, 0.f, 0.f, 0.f};
      }
      // compute this unit from Bs[kh]
      {
        const char* Bb = (const char*)(kh ? Bs1 : Bs0);
        #pragma unroll
        for (int kk = 0; kk < 4; ++kk) {
          #pragma unroll
          for (int nt = 0; nt < 4; ++nt) {
            short8 bfr = *(const short8*)(Bb + (hb + nt * 16 + col) * ROW_B
                                          + kk * 64 + quad * 16);
            acc[0][nt] = __builtin_amdgcn_mfma_f32_16x16x32_bf16(
                A[0][kh * 4 + kk], bfr, acc[0][nt], 0, 0, 0);
            acc[1][nt] = __builtin_amdgcn_mfma_f32_16x16x32_bf16(
                A[1][kh * 4 + kk], bfr, acc[1][nt], 0, 0, 0);
          }
        }
      }
      // deposit prefetched unit into the other buffer
      if (doStage) {
        char* l = (char*)(kh ? Bs0 : Bs1) + w * WAVE_B;
        *(uint4*)(l + lane * 16)        = q0;
        *(uint4*)(l + 1024 + lane * 16) = q1;
        *(uint4*)(l + 2048 + lane * 16) = q2;
        *(uint4*)(l + 3072 + lane * 16) = q3;
        *(unsigned*)(l + 4096 + lane * 4) = q4;
      }
      // epilogue after second half
      if (kh == 1) {
        float bias[4];
        #pragma unroll
        for (int nt = 0; nt < 4; ++nt)
          bias[nt] = biasLds[e * 128 + hb + nt * 16 + col];
        if (e < 4) {
          #pragma unroll
          for (int mt = 0; mt < 2; ++mt) {
            int rb = mg * 32 + mt * 16 + quad * 4;
            float4 g0 = *(const float4*)&gatesL[e * 132 + rb];
            float4 g1 = *(const float4*)&gatesL[(8 + e) * 132 + rb];
            #pragma unroll
            for (int nt = 0; nt < 4; ++nt)
              #pragma unroll
              for (int r = 0; r < 4; ++r) {
                float v = fmaxf(acc[mt][nt][r] + bias[nt], 0.f);
                tw[0][mt][nt][r] += ((const float*)&g0)[r] * v;
                tw[1][mt][nt][r] += ((const float*)&g1)[r] * v;
              }
          }
        } else {
          const int t  = (e - 4) >> 2;
          const int gc = t * 8 + 4 + ((e - 4) & 3);
          #pragma unroll
          for (int mt = 0; mt < 2; ++mt) {
            int rb = mg * 32 + mt * 16 + quad * 4;
            float4 g = *(const float4*)&gatesL[gc * 132 + rb];
            #pragma unroll
            for (int nt = 0; nt < 4; ++nt)
              #pragma unroll
              for (int r = 0; r < 4; ++r) {
                float v = fmaxf(acc[mt][nt][r] + bias[nt], 0.f);
                tw[t][mt][nt][r] += ((const float*)&g)[r] * v;
              }
          }
        }
      }
      __syncthreads();
    }
  }

  // ---- write towers: out[t][row][h] ----
  #pragma unroll
  for (int t = 0; t < 2; ++t)
    #pragma unroll
    for (int mt = 0; mt < 2; ++mt)
      #pragma unroll
      for (int r = 0; r < 4; ++r) {
        size_t row = (size_t)blk * 128 + mg * 32 + mt * 16 + quad * 4 + r;
        float* op = out + ((size_t)t << 22) + row * 128 + hb;
        #pragma unroll
        for (int nt = 0; nt < 4; ++nt)
          op[nt * 16 + col] = tw[t][mt][nt][r];
      }
}

// ---------------------------------------------------------------------------
extern "C" void kernel_launch(void* const* d_in, const int* in_sizes, int n_in,
                              void* d_out, int out_size, void* d_ws, size_t ws_size,
                              hipStream_t stream) {
  const float* x       = (const float*)d_in[0];
  const float* W_share = (const float*)d_in[1];
  const float* b_share = (const float*)d_in[2];
  const float* W_task  = (const float*)d_in[3];
  const float* b_task  = (const float*)d_in[4];
  const float* W_gate  = (const float*)d_in[5];
  const float* b_gate  = (const float*)d_in[6];
  float* out = (float*)d_out;
  unsigned short* WT = (unsigned short*)d_ws;

  int NC = (int)(ws_size / (size_t)COPY_B);
  if (NC < 1) NC = 1;
  if (NC > 4) NC = 4;

  prep_kernel<<<97, 256, 0, stream>>>(W_share, W_task, W_gate, WT, NC);
  dmoe_main<<<256, 512, 0, stream>>>(x, WT, b_share, b_task, b_gate, out, NC);
}

// Round 7
// 156.493 us; speedup vs baseline: 1.2249x; 1.2249x over previous
//
#include <hip/hip_runtime.h>

// DMoE (PLE/CGC) fused kernel for MI355X (gfx950).
// B=32768, D_IN=256, H=128, N_TASK=2, N_EXP=4, N_SHARE=4.
//
// R7 = R6 with compile fix (__builtin_nontemporal_load needs a native
// ext_vector_type, not HIP_vector_type).
// R6: spill-elimination test. R5 skeleton (BM=128, 512 thr, reg-pipelined
// half-expert LDS double-buffer, A resident) with:
//  - t-split (block owns ONE task): tw 64->32 regs => live set ~162 reg,
//    comfortably under the (512,2) cap of 256. No spills.
//  - XCD affinity: XCD = blk%8, task = blk&1 -> each XCD's L2 serves one task.
//  - nontemporal x loads + out stores (keep weight image L2-resident).
//  - NC=2 replicated weight copies, per-block expert rotation.

typedef __attribute__((ext_vector_type(8))) short short8;   // 8 x bf16
typedef __attribute__((ext_vector_type(4))) float float4v;  // MFMA C/D + nt loads

#define ROW_US     136        // 128 data + 8 pad (bf16)
#define ROW_B      272
#define UNIT_US    17408      // 128 rows x 136 (half-expert: 128h x 128k)
#define UNIT_B     34816
#define WAVE_B     4352       // UNIT_B / 8 waves
#define WGT_OFF_US 417792     // 24 * 17408
#define COPY_US    421888     // + 16*256 gate ushorts
#define COPY_B     843776

__device__ __forceinline__ unsigned short f2bf(float f) {
  unsigned u = __builtin_bit_cast(unsigned, f);
  u += 0x7FFFu + ((u >> 16) & 1u);   // round-to-nearest-even
  return (unsigned short)(u >> 16);
}

__device__ __forceinline__ int slot2e(int sr, int t) {
  return (sr < 4) ? sr : 4 + t * 4 + (sr - 4);
}

// ---------------------------------------------------------------------------
// Prep: WT[c][e][kh] units (128h x 136k bf16) + WgT[16][256] per copy.
__global__ __launch_bounds__(256)
void prep_kernel(const float* __restrict__ Ws,
                 const float* __restrict__ Wt,
                 const float* __restrict__ Wg,
                 unsigned short* __restrict__ WT, int NC) {
  int bid = blockIdx.x;
  int tid = threadIdx.x;
  if (bid < 96) {
    __shared__ float tile[64][65];
    int e  = bid >> 3;
    int kt = (bid >> 1) & 3;   // 64-wide k tile; kh = kt>>1
    int ht = bid & 1;          // h half
    const float* src = (e < 4) ? Ws + ((size_t)e << 15)
                               : Wt + ((size_t)(e - 4) << 15);
    int m = tid & 15, n = tid >> 4;
    #pragma unroll
    for (int i = 0; i < 4; ++i) {   // coalesced read of src[k][h]
      int kl = i * 16 + n;
      float4 v = *(const float4*)&src[(size_t)(kt * 64 + kl) * 128 + ht * 64 + m * 4];
      tile[kl][m * 4 + 0] = v.x;
      tile[kl][m * 4 + 1] = v.y;
      tile[kl][m * 4 + 2] = v.z;
      tile[kl][m * 4 + 3] = v.w;
    }
    __syncthreads();
    #pragma unroll
    for (int i = 0; i < 4; ++i) {
      int hl = i * 16 + n;
      ushort4 o;
      o.x = f2bf(tile[m * 4 + 0][hl]);
      o.y = f2bf(tile[m * 4 + 1][hl]);
      o.z = f2bf(tile[m * 4 + 2][hl]);
      o.w = f2bf(tile[m * 4 + 3][hl]);
      size_t rowbase = (size_t)(e * 2 + (kt >> 1)) * UNIT_US
                     + (size_t)(ht * 64 + hl) * ROW_US + (kt & 1) * 64;
      for (int c = 0; c < NC; ++c) {
        *(ushort4*)&WT[(size_t)c * COPY_US + rowbase + m * 4] = o;
        if ((kt & 1) == 1 && m < 2) {           // zero row pad [128,136)
          ushort4 z = {0, 0, 0, 0};
          *(ushort4*)&WT[(size_t)c * COPY_US + rowbase + 64 + m * 4] = z;
        }
      }
    }
  } else {
    // gate weights WgT[n][256], n = t*8+g
    #pragma unroll
    for (int it = 0; it < 16; ++it) {
      int j = it * 256 + tid;
      int n = j >> 8, k = j & 255;
      int t = n >> 3, g = n & 7;
      unsigned short v = f2bf(Wg[(size_t)(t * 256 + k) * 8 + g]);
      for (int c = 0; c < NC; ++c)
        WT[(size_t)c * COPY_US + WGT_OFF_US + j] = v;
    }
  }
}

// ---------------------------------------------------------------------------
__global__ __launch_bounds__(512, 2)
void dmoe_main(const float* __restrict__ x,
               const unsigned short* __restrict__ WT,
               const float* __restrict__ b_share,
               const float* __restrict__ b_task,
               const float* __restrict__ b_gate,
               float* __restrict__ out, int NC) {
  __shared__ unsigned short Bs0[UNIT_US];   // 34816 B
  __shared__ unsigned short Bs1[UNIT_US];   // 34816 B
  __shared__ float gatesL[8 * 132];         // [gate-col][row(128)+pad]
  __shared__ float biasLds[8 * 128];        // 4096 B (slot-indexed)

  const int tid  = threadIdx.x;
  const int lane = tid & 63;
  const int w    = tid >> 6;    // wave 0..7
  const int col  = lane & 15;
  const int quad = lane >> 4;
  const int mg   = w >> 1;      // rows [mg*32, mg*32+32)
  const int ng   = w & 1;       // h    [ng*64, ng*64+64)
  const int blk  = blockIdx.x;
  const int t    = blk & 1;     // task (== XCD parity: one task per XCD)
  const int rt   = blk >> 1;    // row tile (128 rows)
  const int rot  = (blk >> 3) & 7;

  const char* WTc = (const char*)WT + (size_t)((blk >> 3) % NC) * COPY_B;

  // ---- issue first unit's loads first (longest latency) ----
  const int e0 = slot2e(rot, t);
  uint4 p0, p1, p2, p3; unsigned p4;
  {
    const char* g = WTc + (size_t)(e0 * 2) * UNIT_B + w * WAVE_B;
    p0 = *(const uint4*)(g + lane * 16);
    p1 = *(const uint4*)(g + 1024 + lane * 16);
    p2 = *(const uint4*)(g + 2048 + lane * 16);
    p3 = *(const uint4*)(g + 3072 + lane * 16);
    p4 = *(const unsigned*)(g + 4096 + lane * 4);
  }

  // ---- A-fragments: 2 m-tiles x 8 k-steps resident (nontemporal x) ----
  short8 A[2][8];
  {
    const float* xb = x + ((size_t)rt * 128 + mg * 32 + col) * 256 + quad * 8;
    #pragma unroll
    for (int mt = 0; mt < 2; ++mt) {
      const float* xr = xb + (size_t)mt * 16 * 256;
      #pragma unroll
      for (int k = 0; k < 8; ++k) {
        float4v u = __builtin_nontemporal_load((const float4v*)(xr + k * 32));
        float4v v = __builtin_nontemporal_load((const float4v*)(xr + k * 32 + 4));
        short8 fr;
        fr[0] = (short)f2bf(u[0]); fr[1] = (short)f2bf(u[1]);
        fr[2] = (short)f2bf(u[2]); fr[3] = (short)f2bf(u[3]);
        fr[4] = (short)f2bf(v[0]); fr[5] = (short)f2bf(v[1]);
        fr[6] = (short)f2bf(v[2]); fr[7] = (short)f2bf(v[3]);
        A[mt][k] = fr;
      }
    }
  }

  // ---- biases -> LDS (slot-indexed: 0..3 shared, 4..7 this task) ----
  for (int i = tid; i < 1024; i += 512) {
    int sr = i >> 7, h = i & 127;
    biasLds[i] = (sr < 4) ? b_share[sr * 128 + h]
                          : b_task[(size_t)(t * 4 + (sr - 4)) * 128 + h];
  }

  // ---- gates: this task's 8 logit cols (cols 8..15 duplicate 0..7) ----
  {
    const unsigned short* WgT = (const unsigned short*)(WTc + WGT_OFF_US * 2);
    const int gr = col & 7;
    const unsigned short* bp = WgT + (size_t)(t * 8 + gr) * 256 + quad * 8;
    short8 Bg[8];
    #pragma unroll
    for (int k = 0; k < 8; ++k) Bg[k] = *(const short8*)(bp + k * 32);
    float bg = b_gate[t * 8 + gr];
    #pragma unroll
    for (int mt = 0; mt < 2; ++mt) {
      float4v ag = {0.f, 0.f, 0.f, 0.f};
      #pragma unroll
      for (int k = 0; k < 8; ++k)
        ag = __builtin_amdgcn_mfma_f32_16x16x32_bf16(A[mt][k], Bg[k], ag, 0, 0, 0);
      #pragma unroll
      for (int r = 0; r < 4; ++r) {
        float vlog = ag[r] + bg;
        float m = vlog;                      // softmax over 8 cols
        m = fmaxf(m, __shfl_xor(m, 1));
        m = fmaxf(m, __shfl_xor(m, 2));
        m = fmaxf(m, __shfl_xor(m, 4));
        float p = __expf(vlog - m);
        float s = p;
        s += __shfl_xor(s, 1);
        s += __shfl_xor(s, 2);
        s += __shfl_xor(s, 4);
        if (ng == 0 && col < 8)
          gatesL[col * 132 + mg * 32 + mt * 16 + quad * 4 + r] = p / s;
      }
    }
  }

  // ---- deposit first unit into Bs0 ----
  {
    char* l = (char*)Bs0 + w * WAVE_B;
    *(uint4*)(l + lane * 16)        = p0;
    *(uint4*)(l + 1024 + lane * 16) = p1;
    *(uint4*)(l + 2048 + lane * 16) = p2;
    *(uint4*)(l + 3072 + lane * 16) = p3;
    *(unsigned*)(l + 4096 + lane * 4) = p4;
  }
  __syncthreads();

  // ---- accumulators (task-local) ----
  float tw[2][4][4];   // [mt][nt][r]
  #pragma unroll
  for (int mt = 0; mt < 2; ++mt)
    #pragma unroll
    for (int nt = 0; nt < 4; ++nt)
      #pragma unroll
      for (int r = 0; r < 4; ++r)
        tw[mt][nt][r] = 0.f;

  const int hb = ng * 64;
  float4v acc[2][4];

  // ---- slot loop: 8 experts x 2 k-halves; buffer = kh (compile-time) ----
  #pragma unroll 1
  for (int s = 0; s < 8; ++s) {
    const int sr  = (s + rot) & 7;
    const int e   = slot2e(sr, t);
    const int sr2 = (s + 1 + rot) & 7;
    const int e2  = slot2e(sr2, t);
    #pragma unroll
    for (int kh = 0; kh < 2; ++kh) {
      // prefetch next unit
      uint4 q0, q1, q2, q3; unsigned q4;
      const bool doStage = !(s == 7 && kh == 1);
      if (doStage) {
        const int un = (kh == 0) ? (e * 2 + 1) : (e2 * 2);
        const char* g = WTc + (size_t)un * UNIT_B + w * WAVE_B;
        q0 = *(const uint4*)(g + lane * 16);
        q1 = *(const uint4*)(g + 1024 + lane * 16);
        q2 = *(const uint4*)(g + 2048 + lane * 16);
        q3 = *(const uint4*)(g + 3072 + lane * 16);
        q4 = *(const unsigned*)(g + 4096 + lane * 4);
      }
      if (kh == 0) {
        #pragma unroll
        for (int mt = 0; mt < 2; ++mt)
          #pragma unroll
          for (int nt = 0; nt < 4; ++nt)
            acc[mt][nt] = (float4v){0.f, 0.f, 0.f, 0.f};
      }
      // compute this unit from Bs[kh]
      {
        const char* Bb = (const char*)(kh ? Bs1 : Bs0);
        #pragma unroll
        for (int kk = 0; kk < 4; ++kk) {
          #pragma unroll
          for (int nt = 0; nt < 4; ++nt) {
            short8 bfr = *(const short8*)(Bb + (hb + nt * 16 + col) * ROW_B
                                          + kk * 64 + quad * 16);
            acc[0][nt] = __builtin_amdgcn_mfma_f32_16x16x32_bf16(
                A[0][kh * 4 + kk], bfr, acc[0][nt], 0, 0, 0);
            acc[1][nt] = __builtin_amdgcn_mfma_f32_16x16x32_bf16(
                A[1][kh * 4 + kk], bfr, acc[1][nt], 0, 0, 0);
          }
        }
      }
      // deposit prefetched unit into the other buffer
      if (doStage) {
        char* l = (char*)(kh ? Bs0 : Bs1) + w * WAVE_B;
        *(uint4*)(l + lane * 16)        = q0;
        *(uint4*)(l + 1024 + lane * 16) = q1;
        *(uint4*)(l + 2048 + lane * 16) = q2;
        *(uint4*)(l + 3072 + lane * 16) = q3;
        *(unsigned*)(l + 4096 + lane * 4) = q4;
      }
      // epilogue after second half
      if (kh == 1) {
        #pragma unroll
        for (int mt = 0; mt < 2; ++mt) {
          int rb = mg * 32 + mt * 16 + quad * 4;
          float4 g = *(const float4*)&gatesL[sr * 132 + rb];
          #pragma unroll
          for (int nt = 0; nt < 4; ++nt) {
            float bias = biasLds[sr * 128 + hb + nt * 16 + col];
            #pragma unroll
            for (int r = 0; r < 4; ++r) {
              float v = fmaxf(acc[mt][nt][r] + bias, 0.f);
              tw[mt][nt][r] += ((const float*)&g)[r] * v;
            }
          }
        }
      }
      __syncthreads();
    }
  }

  // ---- write towers (nontemporal): out[t][row][h] ----
  #pragma unroll
  for (int mt = 0; mt < 2; ++mt)
    #pragma unroll
    for (int r = 0; r < 4; ++r) {
      size_t row = (size_t)rt * 128 + mg * 32 + mt * 16 + quad * 4 + r;
      float* op = out + ((size_t)t << 22) + row * 128 + hb;
      #pragma unroll
      for (int nt = 0; nt < 4; ++nt)
        __builtin_nontemporal_store(tw[mt][nt][r], op + nt * 16 + col);
    }
}

// ---------------------------------------------------------------------------
extern "C" void kernel_launch(void* const* d_in, const int* in_sizes, int n_in,
                              void* d_out, int out_size, void* d_ws, size_t ws_size,
                              hipStream_t stream) {
  const float* x       = (const float*)d_in[0];
  const float* W_share = (const float*)d_in[1];
  const float* b_share = (const float*)d_in[2];
  const float* W_task  = (const float*)d_in[3];
  const float* b_task  = (const float*)d_in[4];
  const float* W_gate  = (const float*)d_in[5];
  const float* b_gate  = (const float*)d_in[6];
  float* out = (float*)d_out;
  unsigned short* WT = (unsigned short*)d_ws;

  int NC = (int)(ws_size / (size_t)COPY_B);
  if (NC < 1) NC = 1;
  if (NC > 2) NC = 2;

  prep_kernel<<<97, 256, 0, stream>>>(W_share, W_task, W_gate, WT, NC);
  dmoe_main<<<512, 512, 0, stream>>>(x, WT, b_share, b_task, b_gate, out, NC);
}